// Round 8
// baseline (233.017 us; speedup 1.0000x reference)
//
#include <hip/hip_runtime.h>
#include <hip/hip_bf16.h>
#include <math.h>

#define BB 16
#define TT 2048
#define VV 512

typedef __attribute__((ext_vector_type(8))) short short8;
typedef __attribute__((ext_vector_type(4))) float floatx4;

static __device__ inline ushort f2bf(float f) {
  __hip_bfloat16 h = __float2bfloat16(f);
  return *(ushort*)&h;
}

// async 16B global->LDS DMA. LDS dest = wave-uniform base + lane*16;
// global source is per-lane.
static __device__ __forceinline__ void cp16(const void* g, void* l) {
  __builtin_amdgcn_global_load_lds((const __attribute__((address_space(1))) void*)g,
                                   (__attribute__((address_space(3))) void*)l, 16, 0, 0);
}

// ---------------- builders (unchanged) ----------------

__global__ __launch_bounds__(256) void k_transpose_wq(const float* __restrict__ Wq,
                                                      ushort* __restrict__ WqT) {
  int u = blockIdx.x;
  for (int v = threadIdx.x; v < VV; v += blockDim.x)
    WqT[u * VV + v] = f2bf(Wq[(size_t)v * VV + u]);
}

__global__ __launch_bounds__(256) void k_build_pe(const float* __restrict__ h,
                                                  ushort* __restrict__ PE) {
  int t = blockIdx.x;
  ushort* out = PE + (size_t)t * TT;
  for (int p = threadIdx.x; p < TT; p += blockDim.x)
    out[p] = (p <= t) ? f2bf(h[t - p]) : (ushort)0;
}

// M[b,u,p] = WqT[u, idx[b,p]] ; VvT[b,j,s] = Wv[j, idx[b,s]]
__global__ __launch_bounds__(256) void k_build_mv(const int* __restrict__ idx,
                                                  const float* __restrict__ Wv,
                                                  const ushort* __restrict__ WqT,
                                                  ushort* __restrict__ M,
                                                  ushort* __restrict__ VvT) {
  int bv = blockIdx.x;
  int b = bv >> 9, v = bv & (VV - 1);
  __shared__ float wrow[VV];
  __shared__ ushort qrow[VV];
  for (int u = threadIdx.x; u < VV; u += blockDim.x) {
    wrow[u] = Wv[(size_t)v * VV + u];
    qrow[u] = WqT[(size_t)v * VV + u];
  }
  __syncthreads();
  const int* row = idx + b * TT;
  ushort* om = M + (size_t)bv * TT;
  ushort* ov = VvT + (size_t)bv * TT;
  for (int s4 = threadIdx.x * 4; s4 < TT; s4 += blockDim.x * 4) {
    int4 iv = *(const int4*)(row + s4);
    ushort4 m, w;
    m.x = qrow[iv.x];  w.x = f2bf(wrow[iv.x]);
    m.y = qrow[iv.y];  w.y = f2bf(wrow[iv.y]);
    m.z = qrow[iv.z];  w.z = f2bf(wrow[iv.z]);
    m.w = qrow[iv.w];  w.w = f2bf(wrow[iv.w]);
    *(ushort4*)(om + s4) = m;
    *(ushort4*)(ov + s4) = w;
  }
}

// Pre-masked diagonal tiles (unchanged, 128x128 granularity):
// a2d[b][tt128][r][c] = (c<=r) ? GT[b, idx[b,t0+r], t0+c] : 0
__global__ __launch_bounds__(256) void k_diag(const int* __restrict__ idx,
                                              const ushort* __restrict__ GT,
                                              ushort* __restrict__ a2d) {
  const int t_t = blockIdx.x, b = blockIdx.y;
  const int t0 = t_t << 7;
  ushort* outt = a2d + (((size_t)(b << 4) + t_t) << 14);
  for (int e = threadIdx.x; e < 2048; e += 256) {
    const int r = e >> 4;
    const int c8 = (e & 15) << 3;
    const int u = idx[(b << 11) + t0 + r];
    const ushort* src = GT + ((size_t)((b << 9) + u)) * TT + t0 + c8;
    ushort4 lo = *(const ushort4*)(src);
    ushort4 hi = *(const ushort4*)(src + 4);
    ushort vals[8] = {lo.x, lo.y, lo.z, lo.w, hi.x, hi.y, hi.z, hi.w};
    ushort o[8];
#pragma unroll
    for (int k = 0; k < 8; ++k) o[k] = (c8 + k <= r) ? vals[k] : (ushort)0;
    *(ushort4*)(outt + r * 128 + c8) = *(ushort4*)&o[0];
    *(ushort4*)(outt + r * 128 + c8 + 4) = *(ushort4*)&o[4];
  }
}

// ---------------- 256x128 MFMA GEMM core, 8 waves, 4-slot ring ------------
// Tile: 256 rows x 128 cols, BK=32. 8 waves in 4x2 grid, wave = 64x64 (4x4
// 16x16 frags). LDS: A 4 slots x 16 KB + B 4 slots x 8 KB = 96 KB -> 1
// block/CU, 2 waves/SIMD. Counted pipeline: prefetch depth 3 (3 stages x 3
// cp16/thread in flight), wait vmcnt(6)->oldest stage landed, single
// s_barrier per k-step, setprio around MFMA cluster. Uniform pair-blocks
// (complementary causal tiles) -> every block identical k-step count.
// XCD pinned by b (h&7) -> per-batch operands live in one L2 (R7-verified).

#define PRELUDE8()                                                             \
  __shared__ __attribute__((aligned(16))) short As[4 * 8192];                  \
  __shared__ __attribute__((aligned(16))) short Bs[4 * 4096];                  \
  const int tid = threadIdx.x;                                                 \
  const int lane = tid & 63;                                                   \
  const int wid = tid >> 6;                                                    \
  const int wm = wid >> 1, wn = wid & 1;                                       \
  const int quad = lane >> 4, ln = lane & 15;                                  \
  const int rr = tid >> 2;                                                     \
  const int cg = (((tid & 3) ^ (rr & 3)) << 3);                                \
  const short* ap[4];                                                          \
  const short* bp[4];                                                          \
  _Pragma("unroll") for (int i = 0; i < 4; i++)                                \
      ap[i] = &As[(wm * 64 + i * 16 + ln) * 32 + ((quad ^ (ln & 3)) << 3)];    \
  _Pragma("unroll") for (int j = 0; j < 4; j++)                                \
      bp[j] = &Bs[(wn * 64 + j * 16 + ln) * 32 + ((quad ^ (ln & 3)) << 3)];

#define COMP8(c)                                                               \
  {                                                                            \
    const int _oa = (c) << 13, _ob = (c) << 12;                                \
    short8 af[4], bfr[4];                                                      \
    _Pragma("unroll") for (int i = 0; i < 4; i++)                              \
        af[i] = *(const short8*)(ap[i] + _oa);                                 \
    _Pragma("unroll") for (int j = 0; j < 4; j++)                              \
        bfr[j] = *(const short8*)(bp[j] + _ob);                                \
    _Pragma("unroll") for (int i = 0; i < 4; i++)                              \
        _Pragma("unroll") for (int j = 0; j < 4; j++)                          \
            acc[i][j] = __builtin_amdgcn_mfma_f32_16x16x32_bf16(               \
                af[i], bfr[j], acc[i][j], 0, 0, 0);                            \
  }

#define ZERO_ACC()                                                             \
  _Pragma("unroll") for (int i = 0; i < 4; i++)                                \
      _Pragma("unroll") for (int j = 0; j < 4; j++)                            \
          acc[i][j] = (floatx4){0.f, 0.f, 0.f, 0.f};

// STAGE_AT(slot, k): 3 cp16 per thread (A rows 0..127, A rows 128..255, B).
#define PIPE8(NK, STAGE_AT)                                                    \
  {                                                                            \
    STAGE_AT(0, 0);                                                            \
    STAGE_AT(1, 1);                                                            \
    STAGE_AT(2, 2);                                                            \
    int cur = 0, pf = 3;                                                       \
    _Pragma("unroll 1") for (int kt = 0; kt < (NK); ++kt) {                    \
      const int rem = (NK)-1 - kt;                                             \
      if (rem >= 2) {                                                          \
        asm volatile("s_waitcnt vmcnt(6)" ::: "memory");                       \
      } else if (rem == 1) {                                                   \
        asm volatile("s_waitcnt vmcnt(3)" ::: "memory");                       \
      } else {                                                                 \
        asm volatile("s_waitcnt vmcnt(0)" ::: "memory");                       \
      }                                                                        \
      __builtin_amdgcn_sched_barrier(0);                                       \
      __builtin_amdgcn_s_barrier();                                            \
      __builtin_amdgcn_sched_barrier(0);                                       \
      if (kt + 3 < (NK)) STAGE_AT(pf, kt + 3);                                 \
      __builtin_amdgcn_sched_barrier(0);                                       \
      __builtin_amdgcn_s_setprio(1);                                           \
      COMP8(cur);                                                              \
      __builtin_amdgcn_s_setprio(0);                                           \
      cur = (cur + 1) & 3;                                                     \
      pf = (pf + 1) & 3;                                                       \
    }                                                                          \
  }

// GT[b,u,s] = sum_p M[b,u,p] * PE[s,p].  A = M (256 u-rows), B = PE (128
// s-rows), causal K-extent p < 128*(st+1) -> nk = 4*(st+1). Pair (st, 15-st)
// -> uniform 68 k-steps. Grid 256 = 1/CU; XCD pin by b.
__global__ __launch_bounds__(512) void k_gemm_gt(const ushort* __restrict__ M,
                                                 const ushort* __restrict__ PE,
                                                 ushort* __restrict__ GT) {
  const int h = blockIdx.x;
  const int b = (h & 7) | ((h >> 7) << 3);
  const int u2t = (h >> 3) & 1;
  const int pr = (h >> 4) & 7;
  const int u0 = u2t << 8;
  PRELUDE8();
  const ushort* a_m0 = M + ((size_t)((b << 9) + u0 + rr)) * TT + cg;
  const ushort* a_m1 = a_m0 + (size_t)128 * TT;
  floatx4 acc[4][4];
#pragma unroll 1
  for (int half = 0; half < 2; ++half) {
    const int st = half ? (15 - pr) : pr;
    const int s0 = st << 7;
    const int nk = (st << 2) + 4;
    const ushort* b_pe = PE + (size_t)(s0 + rr) * TT + cg;
    ZERO_ACC();
#define SA_GT(c, k)                                                            \
  {                                                                            \
    cp16(a_m0 + ((k) << 5), &As[((c) << 13) + tid * 8]);                       \
    cp16(a_m1 + ((k) << 5), &As[((c) << 13) + 4096 + tid * 8]);                \
    cp16(b_pe + ((k) << 5), &Bs[((c) << 12) + tid * 8]);                       \
  }
    PIPE8(nk, SA_GT);
#undef SA_GT
#pragma unroll
    for (int i = 0; i < 4; i++)
#pragma unroll
      for (int j = 0; j < 4; j++) {
        const int rowb = u0 + wm * 64 + i * 16 + quad * 4;
        const int col = s0 + wn * 64 + j * 16 + ln;
#pragma unroll
        for (int r = 0; r < 4; r++)
          GT[((size_t)((b << 9) + rowb + r)) * TT + col] = f2bf(acc[i][j][r]);
      }
    __syncthreads();  // all slot readers done before next half's re-stage
  }
}

// logits[b,t,j] = sum_{s<=t} GT[b, idx[b,t], s] * VvT[b,j,s]
// 256-row t-tiles tt (paired tt, 7-tt -> uniform 72 k-steps), 128-col j.
// Per k-step k (s in [32k,32k+32)), per 128-row half of the A tile:
//   upper rows (t in [256tt,256tt+128)):  k < 8tt       -> gathered GT rows
//                                         k in [8tt,+4) -> a2d tile 2tt
//                                         else          -> zeros (PE row0 hi)
//   lower rows:                           k < 8tt+4     -> gathered GT rows
//                                         else          -> a2d tile 2tt+1
__global__ __launch_bounds__(512) void k_gemm2(const int* __restrict__ idx,
                                               const ushort* __restrict__ GT,
                                               const ushort* __restrict__ a2d,
                                               const ushort* __restrict__ VvT,
                                               const ushort* __restrict__ PE,
                                               float* __restrict__ out) {
  const int h = blockIdx.x;
  const int b = (h & 7) | ((h >> 7) << 3);
  const int j_t = (h >> 3) & 3;
  const int pr = (h >> 5) & 3;
  const int j0 = j_t << 7;
  PRELUDE8();
  const ushort* b_vv = VvT + ((size_t)((b << 9) + j0 + rr)) * TT + cg;
  const ushort* zsrc = PE + 1024 + cg;  // PE row 0, cols >=1024: all zero
  floatx4 acc[4][4];
#pragma unroll 1
  for (int half = 0; half < 2; ++half) {
    const int tt = half ? (7 - pr) : pr;
    const int t0 = tt << 8;
    const int nk8 = tt << 3;
    const int nk = nk8 + 8;
    const int u_up = idx[(b << 11) + t0 + rr];
    const int u_dn = idx[(b << 11) + t0 + 128 + rr];
    const ushort* a_gt_up = GT + ((size_t)(b << 9) + u_up) * TT + cg;
    const ushort* a_gt_dn = GT + ((size_t)(b << 9) + u_dn) * TT + cg;
    const ushort* ad_up =
        a2d + (((size_t)(b << 4) + 2 * tt) << 14) + (size_t)rr * 128 + cg;
    const ushort* ad_dn =
        a2d + (((size_t)(b << 4) + 2 * tt + 1) << 14) + (size_t)rr * 128 + cg;
    ZERO_ACC();
#define SA_G2(c, k)                                                            \
  {                                                                            \
    const ushort* _au = (k) < nk8 ? a_gt_up + ((k) << 5)                       \
                        : ((k) < nk8 + 4 ? ad_up + (((k)-nk8) << 5) : zsrc);   \
    const ushort* _ad = (k) < nk8 + 4 ? a_gt_dn + ((k) << 5)                   \
                                      : ad_dn + (((k)-nk8 - 4) << 5);          \
    cp16(_au, &As[((c) << 13) + tid * 8]);                                     \
    cp16(_ad, &As[((c) << 13) + 4096 + tid * 8]);                              \
    cp16(b_vv + ((k) << 5), &Bs[((c) << 12) + tid * 8]);                       \
  }
    PIPE8(nk, SA_G2);
#undef SA_G2
#pragma unroll
    for (int i = 0; i < 4; i++)
#pragma unroll
      for (int j = 0; j < 4; j++) {
        const int rowb = t0 + wm * 64 + i * 16 + quad * 4;
        const int col = j0 + wn * 64 + j * 16 + ln;
#pragma unroll
        for (int r = 0; r < 4; r++)
          out[((size_t)((b << 11) + rowb + r)) * VV + col] = acc[i][j][r];
      }
    __syncthreads();  // all slot readers done before next half's re-stage
  }
}

extern "C" void kernel_launch(void* const* d_in, const int* in_sizes, int n_in,
                              void* d_out, int out_size, void* d_ws, size_t ws_size,
                              hipStream_t stream) {
  const int* idx = (const int*)d_in[0];
  const float* pos_table = (const float*)d_in[1];
  const float* Wq = (const float*)d_in[2];
  const float* Wv = (const float*)d_in[3];
  float* out = (float*)d_out;

  char* ws = (char*)d_ws;
  // ws layout (bytes):
  //   WqT bf16 (V,V)        :         0 ..    524288
  //   PE  bf16 (T,T)        :    524288 ..   8912896
  //   M   bf16 (B,V,T)      :   8912896 ..  42467328
  //   VvT bf16 (B,V,T)      :  42467328 ..  76021760
  //   GT  bf16 (B,V,T)      :  76021760 .. 109576192
  //   a2d bf16 (B,16,128^2) : 109576192 .. 117964800
  ushort* WqT = (ushort*)(ws);
  ushort* PE = (ushort*)(ws + 524288UL);
  ushort* M = (ushort*)(ws + 8912896UL);
  ushort* VvT = (ushort*)(ws + 42467328UL);
  ushort* GT = (ushort*)(ws + 76021760UL);
  ushort* a2d = (ushort*)(ws + 109576192UL);

  k_transpose_wq<<<dim3(VV), 256, 0, stream>>>(Wq, WqT);
  k_build_pe<<<dim3(TT), 256, 0, stream>>>(pos_table, PE);
  k_build_mv<<<dim3(BB * VV), 256, 0, stream>>>(idx, Wv, WqT, M, VvT);
  k_gemm_gt<<<dim3(256), 512, 0, stream>>>(M, PE, GT);
  k_diag<<<dim3(16, BB), 256, 0, stream>>>(idx, GT, a2d);
  k_gemm2<<<dim3(256), 512, 0, stream>>>(idx, GT, a2d, VvT, PE, out);
}

// Round 9
// 194.927 us; speedup vs baseline: 1.1954x; 1.1954x over previous
//
#include <hip/hip_runtime.h>
#include <hip/hip_bf16.h>
#include <math.h>

#define BB 16
#define TT 2048
#define VV 512

typedef __attribute__((ext_vector_type(8))) short short8;
typedef __attribute__((ext_vector_type(4))) float floatx4;

static __device__ inline ushort f2bf(float f) {
  __hip_bfloat16 h = __float2bfloat16(f);
  return *(ushort*)&h;
}

// async 16B global->LDS DMA. LDS dest = wave-uniform base + lane*16;
// global source is per-lane.
static __device__ __forceinline__ void cp16(const void* g, void* l) {
  __builtin_amdgcn_global_load_lds((const __attribute__((address_space(1))) void*)g,
                                   (__attribute__((address_space(3))) void*)l, 16, 0, 0);
}

// Banded balanced XCD-pinned decode for the GEMM grids (1024 blocks).
// xcd = h&7 (verified: block h lands on XCD h%8). rank = h>>3 in [0,128)
// arrives in order per XCD; CU cc (= rank%32) receives one job per band:
// t = {15-g, 11-g, 4+g, g} with g = cc>>3  =>  per-CU K-steps
// (4t+4 each) sum to exactly 136 for every CU. slot = cc&7 encodes
// (b_hi, col-tile); b = xcd | b_hi<<3 keeps all of batch b's operands in
// one XCD's L2 (R7-verified: FETCH 233->37 MB).
static __device__ __forceinline__ void band_map(int h, int* b, int* ct, int* tt) {
  const int xcd = h & 7, rank = h >> 3;
  const int band = rank >> 5, cc = rank & 31, g = cc >> 3, slot = cc & 7;
  *b = xcd | ((slot >> 2) << 3);
  *ct = slot & 3;
  *tt = (band == 0) ? (15 - g) : (band == 1) ? (11 - g) : (band == 2) ? (4 + g) : g;
}

// ---------------- builders ----------------

__global__ __launch_bounds__(256) void k_transpose_wq(const float* __restrict__ Wq,
                                                      ushort* __restrict__ WqT) {
  int u = blockIdx.x;
  for (int v = threadIdx.x; v < VV; v += blockDim.x)
    WqT[u * VV + v] = f2bf(Wq[(size_t)v * VV + u]);
}

__global__ __launch_bounds__(256) void k_build_pe(const float* __restrict__ h,
                                                  ushort* __restrict__ PE) {
  int t = blockIdx.x;
  ushort* out = PE + (size_t)t * TT;
  for (int p = threadIdx.x; p < TT; p += blockDim.x)
    out[p] = (p <= t) ? f2bf(h[t - p]) : (ushort)0;
}

// M[b,u,p] = WqT[u, idx[b,p]] ; VvT[b,j,s] = Wv[j, idx[b,s]]
// XCD-pinned by b so the dirty M/VvT lines live in the consumer's L2.
__global__ __launch_bounds__(256) void k_build_mv(const int* __restrict__ idx,
                                                  const float* __restrict__ Wv,
                                                  const ushort* __restrict__ WqT,
                                                  ushort* __restrict__ M,
                                                  ushort* __restrict__ VvT) {
  const int h = blockIdx.x;
  const int b = (h & 7) | (((h >> 3) & 1) << 3);
  const int v = h >> 4;
  const int bv = (b << 9) + v;
  __shared__ float wrow[VV];
  __shared__ ushort qrow[VV];
  for (int u = threadIdx.x; u < VV; u += blockDim.x) {
    wrow[u] = Wv[(size_t)v * VV + u];
    qrow[u] = WqT[(size_t)v * VV + u];
  }
  __syncthreads();
  const int* row = idx + b * TT;
  ushort* om = M + (size_t)bv * TT;
  ushort* ov = VvT + (size_t)bv * TT;
  for (int s4 = threadIdx.x * 4; s4 < TT; s4 += blockDim.x * 4) {
    int4 iv = *(const int4*)(row + s4);
    ushort4 m, w;
    m.x = qrow[iv.x];  w.x = f2bf(wrow[iv.x]);
    m.y = qrow[iv.y];  w.y = f2bf(wrow[iv.y]);
    m.z = qrow[iv.z];  w.z = f2bf(wrow[iv.z]);
    m.w = qrow[iv.w];  w.w = f2bf(wrow[iv.w]);
    *(ushort4*)(om + s4) = m;
    *(ushort4*)(ov + s4) = w;
  }
}

// ---------------- 128x128 MFMA GEMM core (R2-verified 2-slot dbuf) -------
// 32 KB LDS -> 4 blocks/CU co-resident with the 1024-block banded grid.
// Per k-step: stage tile k+1 into buf^1, compute tile k, one __syncthreads
// (its implicit vmcnt drain lands the prefetch; cross-block overlap at 4
// streams/CU hides the residual latency -- the m97/m114 mechanism).

#define GEMM_PRELUDE()                                                         \
  __shared__ __attribute__((aligned(16))) short As[2 * 128 * 32];              \
  __shared__ __attribute__((aligned(16))) short Bs[2 * 128 * 32];              \
  const int tid = threadIdx.x;                                                 \
  const int lane = tid & 63;                                                   \
  const int wm = (tid >> 6) & 1, wn = tid >> 7;                                \
  const int quad = lane >> 4, ln = lane & 15;                                  \
  const int rr = tid >> 2;                                                     \
  const int cg = (((tid & 3) ^ (rr & 3)) << 3);                                \
  short* a_dst = &As[tid * 8];                                                 \
  short* b_dst = &Bs[tid * 8];                                                 \
  const short* ap[4];                                                          \
  const short* bp[4];                                                          \
  _Pragma("unroll") for (int i = 0; i < 4; i++)                                \
      ap[i] = &As[(wm * 64 + i * 16 + ln) * 32 + ((quad ^ (ln & 3)) << 3)];    \
  _Pragma("unroll") for (int j = 0; j < 4; j++)                                \
      bp[j] = &Bs[(wn * 64 + j * 16 + ln) * 32 + ((quad ^ (ln & 3)) << 3)];

#define GEMM_STAGE(c, PA0, PA1, PB0, PB1)                                      \
  {                                                                            \
    const int _o = (c) << 12; /* 4096 shorts = one buffer */                   \
    cp16((PA0), a_dst + _o);                                                   \
    cp16((PA1), a_dst + _o + 2048);                                            \
    cp16((PB0), b_dst + _o);                                                   \
    cp16((PB1), b_dst + _o + 2048);                                            \
  }

#define GEMM_COMPUTE(c)                                                        \
  {                                                                            \
    const int _o = (c) << 12;                                                  \
    short8 af[4], bfr[4];                                                      \
    _Pragma("unroll") for (int i = 0; i < 4; i++)                              \
        af[i] = *(const short8*)(ap[i] + _o);                                  \
    _Pragma("unroll") for (int j = 0; j < 4; j++)                              \
        bfr[j] = *(const short8*)(bp[j] + _o);                                 \
    _Pragma("unroll") for (int i = 0; i < 4; i++)                              \
        _Pragma("unroll") for (int j = 0; j < 4; j++)                          \
            acc[i][j] = __builtin_amdgcn_mfma_f32_16x16x32_bf16(               \
                af[i], bfr[j], acc[i][j], 0, 0, 0);                            \
  }

#define ZERO_ACC()                                                             \
  _Pragma("unroll") for (int i = 0; i < 4; i++)                                \
      _Pragma("unroll") for (int j = 0; j < 4; j++)                            \
          acc[i][j] = (floatx4){0.f, 0.f, 0.f, 0.f};

// 2-slot double-buffered loop (R2-verified): stage k+1, compute k, barrier.
#define DBUF_LOOP(NK, STAGE_AT)                                                \
  {                                                                            \
    STAGE_AT(0, 0);                                                            \
    __syncthreads();                                                           \
    int cur = 0;                                                               \
    _Pragma("unroll 1") for (int kt = 0; kt < (NK); ++kt) {                    \
      if (kt + 1 < (NK)) STAGE_AT(cur ^ 1, kt + 1);                            \
      GEMM_COMPUTE(cur);                                                       \
      __syncthreads();                                                         \
      cur ^= 1;                                                                \
    }                                                                          \
  }

// GT[b,u,s] = sum_p M[b,u,p] * PE[s,p]  (causal K-extent: p < 128*(s_t+1))
// Banded grid: ct = u-tile, tt = s-tile, nk = 4*s_t+4; per-CU sum 136.
__global__ __launch_bounds__(256) void k_gemm_gt(const ushort* __restrict__ M,
                                                 const ushort* __restrict__ PE,
                                                 ushort* __restrict__ GT) {
  int b, u_t, s_t;
  band_map(blockIdx.x, &b, &u_t, &s_t);
  const int u0 = u_t << 7, s0 = s_t << 7;
  const int nk = (s_t << 2) + 4;
  GEMM_PRELUDE();
  const ushort* a_src0 = M + ((size_t)((b << 9) + u0 + rr)) * TT + cg;
  const ushort* a_src1 = a_src0 + (size_t)64 * TT;
  const ushort* b_src0 = PE + (size_t)(s0 + rr) * TT + cg;
  const ushort* b_src1 = b_src0 + (size_t)64 * TT;
  floatx4 acc[4][4];
  ZERO_ACC();
#define SA_GT(c, k)                                                            \
  GEMM_STAGE(c, a_src0 + ((k) << 5), a_src1 + ((k) << 5), b_src0 + ((k) << 5), \
             b_src1 + ((k) << 5))
  DBUF_LOOP(nk, SA_GT);
#undef SA_GT
#pragma unroll
  for (int i = 0; i < 4; i++)
#pragma unroll
    for (int j = 0; j < 4; j++) {
      const int rowb = u0 + wm * 64 + i * 16 + quad * 4;
      const int col = s0 + wn * 64 + j * 16 + ln;
#pragma unroll
      for (int r = 0; r < 4; r++)
        GT[((size_t)((b << 9) + rowb + r)) * TT + col] = f2bf(acc[i][j][r]);
    }
}

// Pre-masked diagonal tiles: a2d[b][t_t][r][c] = (c<=r) ? GT[b, idx[b,t0+r], t0+c] : 0
// XCD-pinned by b (reads GT[b] warm, writes a2d[b] into consumer's L2).
__global__ __launch_bounds__(256) void k_diag(const int* __restrict__ idx,
                                              const ushort* __restrict__ GT,
                                              ushort* __restrict__ a2d) {
  const int h = blockIdx.x;
  const int b = (h & 7) | (((h >> 3) & 1) << 3);
  const int t_t = (h >> 4) & 15;
  const int t0 = t_t << 7;
  ushort* outt = a2d + (((size_t)(b << 4) + t_t) << 14);
  for (int e = threadIdx.x; e < 2048; e += 256) {
    const int r = e >> 4;
    const int c8 = (e & 15) << 3;
    const int u = idx[(b << 11) + t0 + r];
    const ushort* src = GT + ((size_t)((b << 9) + u)) * TT + t0 + c8;
    ushort4 lo = *(const ushort4*)(src);
    ushort4 hi = *(const ushort4*)(src + 4);
    ushort vals[8] = {lo.x, lo.y, lo.z, lo.w, hi.x, hi.y, hi.z, hi.w};
    ushort o[8];
#pragma unroll
    for (int k = 0; k < 8; ++k) o[k] = (c8 + k <= r) ? vals[k] : (ushort)0;
    *(ushort4*)(outt + r * 128 + c8) = *(ushort4*)&o[0];
    *(ushort4*)(outt + r * 128 + c8 + 4) = *(ushort4*)&o[4];
  }
}

// logits[b,t,j] = sum_{s<=t} GT[b, idx[b,t], s] * VvT[b,j,s]
// Banded grid: ct = j-tile, tt = t-tile. K-loop unified: kt < nk_main ->
// gathered GT rows (below diagonal); kt >= nk_main -> pre-masked diag tile.
__global__ __launch_bounds__(256) void k_gemm2(const int* __restrict__ idx,
                                               const ushort* __restrict__ GT,
                                               const ushort* __restrict__ a2d,
                                               const ushort* __restrict__ VvT,
                                               float* __restrict__ out) {
  int b, j_t, t_t;
  band_map(blockIdx.x, &b, &j_t, &t_t);
  const int t0 = t_t << 7, j0 = j_t << 7;
  const int nk_main = t_t << 2;
  const int nk = nk_main + 4;
  GEMM_PRELUDE();
  const int u0 = idx[(b << 11) + t0 + rr];
  const int u1 = idx[(b << 11) + t0 + rr + 64];
  const ushort* a_src0 = GT + ((size_t)(b << 9) + u0) * TT + cg;
  const ushort* a_src1 = GT + ((size_t)(b << 9) + u1) * TT + cg;
  const ushort* b_src0 = VvT + ((size_t)((b << 9) + j0 + rr)) * TT + cg;
  const ushort* b_src1 = b_src0 + (size_t)64 * TT;
  const ushort* ad0 = a2d + (((size_t)(b << 4) + t_t) << 14) + (size_t)rr * 128 + cg;
  const ushort* ad1 = ad0 + (size_t)64 * 128;
  floatx4 acc[4][4];
  ZERO_ACC();
#define SA_G2(c, k)                                                            \
  GEMM_STAGE(c,                                                                \
             (k) < nk_main ? a_src0 + ((k) << 5) : ad0 + (((k) - nk_main) << 5), \
             (k) < nk_main ? a_src1 + ((k) << 5) : ad1 + (((k) - nk_main) << 5), \
             b_src0 + ((k) << 5), b_src1 + ((k) << 5))
  DBUF_LOOP(nk, SA_G2);
#undef SA_G2
#pragma unroll
  for (int i = 0; i < 4; i++)
#pragma unroll
    for (int j = 0; j < 4; j++) {
      const int rowb = t0 + wm * 64 + i * 16 + quad * 4;
      const int col = j0 + wn * 64 + j * 16 + ln;
#pragma unroll
      for (int r = 0; r < 4; r++)
        out[((size_t)((b << 11) + rowb + r)) * VV + col] = acc[i][j][r];
    }
}

extern "C" void kernel_launch(void* const* d_in, const int* in_sizes, int n_in,
                              void* d_out, int out_size, void* d_ws, size_t ws_size,
                              hipStream_t stream) {
  const int* idx = (const int*)d_in[0];
  const float* pos_table = (const float*)d_in[1];
  const float* Wq = (const float*)d_in[2];
  const float* Wv = (const float*)d_in[3];
  float* out = (float*)d_out;

  char* ws = (char*)d_ws;
  // ws layout (bytes):
  //   WqT bf16 (V,V)        :         0 ..    524288
  //   PE  bf16 (T,T)        :    524288 ..   8912896
  //   M   bf16 (B,V,T)      :   8912896 ..  42467328
  //   VvT bf16 (B,V,T)      :  42467328 ..  76021760
  //   GT  bf16 (B,V,T)      :  76021760 .. 109576192
  //   a2d bf16 (B,16,128^2) : 109576192 .. 117964800
  ushort* WqT = (ushort*)(ws);
  ushort* PE = (ushort*)(ws + 524288UL);
  ushort* M = (ushort*)(ws + 8912896UL);
  ushort* VvT = (ushort*)(ws + 42467328UL);
  ushort* GT = (ushort*)(ws + 76021760UL);
  ushort* a2d = (ushort*)(ws + 109576192UL);

  k_transpose_wq<<<dim3(VV), 256, 0, stream>>>(Wq, WqT);
  k_build_pe<<<dim3(TT), 256, 0, stream>>>(pos_table, PE);
  k_build_mv<<<dim3(BB * VV), 256, 0, stream>>>(idx, Wv, WqT, M, VvT);
  k_gemm_gt<<<dim3(1024), 256, 0, stream>>>(M, PE, GT);
  k_diag<<<dim3(256), 256, 0, stream>>>(idx, GT, a2d);
  k_gemm2<<<dim3(1024), 256, 0, stream>>>(idx, GT, a2d, VvT, out);
}